// Round 1
// baseline (100.052 us; speedup 1.0000x reference)
//
#include <hip/hip_runtime.h>
#include <hip/hip_bf16.h>

// NT-Xent (SimCLR) loss, B=4096, D=256, N=8192, T=0.5.
// loss = [ sum_i log(sum_{j!=i} exp(sim_ij * 2)) - 4 * sum_{i<B} pos_i ] / N
// sim symmetric => row sums computed as column sums of MFMA tiles (per-lane).

constexpr int BB = 4096;     // batch
constexpr int NN = 8192;     // 2*batch
constexpr int DD = 256;      // feature dim
constexpr int RT = 256;      // r-rows per block (output rows of the reduction)
constexpr int CC = 512;      // c-columns per block chunk
constexpr int NRT = NN / RT; // 32 row tiles
constexpr int NCH = NN / CC; // 16 column chunks
constexpr int CSTEPS = CC / 32;

typedef _Float16 half4v __attribute__((ext_vector_type(4)));
typedef _Float16 half8v __attribute__((ext_vector_type(8)));
typedef float floatx16 __attribute__((ext_vector_type(16)));

// ---------------- Kernel 1: normalize rows -> f16, compute pos partials ------
__global__ __launch_bounds__(256) void nt_normalize(
    const float* __restrict__ zi, const float* __restrict__ zj,
    _Float16* __restrict__ Z, float* __restrict__ posPartial)
{
    const int lane = threadIdx.x & 63;
    const int wave = threadIdx.x >> 6;
    const int i = blockIdx.x * 4 + wave;   // pair index, < BB

    const float4 a = ((const float4*)(zi + (size_t)i * DD))[lane];
    const float4 b = ((const float4*)(zj + (size_t)i * DD))[lane];

    float ssi = a.x*a.x + a.y*a.y + a.z*a.z + a.w*a.w;
    float ssj = b.x*b.x + b.y*b.y + b.z*b.z + b.w*b.w;
    float dd  = a.x*b.x + a.y*b.y + a.z*b.z + a.w*b.w;
#pragma unroll
    for (int off = 32; off > 0; off >>= 1) {
        ssi += __shfl_xor(ssi, off);
        ssj += __shfl_xor(ssj, off);
        dd  += __shfl_xor(dd,  off);
    }
    const float invi = rsqrtf(ssi);
    const float invj = rsqrtf(ssj);

    half4v ha, hb;
    ha.x = (_Float16)(a.x * invi); ha.y = (_Float16)(a.y * invi);
    ha.z = (_Float16)(a.z * invi); ha.w = (_Float16)(a.w * invi);
    hb.x = (_Float16)(b.x * invj); hb.y = (_Float16)(b.y * invj);
    hb.z = (_Float16)(b.z * invj); hb.w = (_Float16)(b.w * invj);

    ((half4v*)(Z + (size_t)i * DD))[lane]        = ha;
    ((half4v*)(Z + (size_t)(BB + i) * DD))[lane] = hb;

    __shared__ float ps[4];
    if (lane == 0) ps[wave] = dd * invi * invj;
    __syncthreads();
    if (threadIdx.x == 0)
        posPartial[blockIdx.x] = ps[0] + ps[1] + ps[2] + ps[3];
}

// ---------------- Kernel 2: fused sim-GEMM + exp + row-sum -------------------
// Grid: NRT * NCH = 512 blocks, 256 threads (4 waves). Each wave owns 64 r-rows
// (2 B-fragment sets of 32 held in registers across whole K=256). c-tiles of 32
// rows staged into LDS (swizzled), K-loop of 16 MFMAs x 2 sets.
__global__ __launch_bounds__(256, 2) void nt_simexp(
    const _Float16* __restrict__ Z, float* __restrict__ rowsum)
{
    __shared__ _Float16 lds[32 * DD];   // 16 KB, row c = 256 elems, 16B-granule swizzled

    const int bid = blockIdx.x;
    const int rt = bid & (NRT - 1);
    const int ch = bid >> 5;            // NRT == 32
    const int tid = threadIdx.x;
    const int wave = tid >> 6;
    const int lane = tid & 63;
    const int lm = lane & 31;           // MFMA row/col index within 32
    const int lh = lane >> 5;           // half select

    const int rbase = rt * RT + wave * 64;  // this wave's 64 r-rows

    // Load B fragments for both 32-row sets, all 16 k-steps, into registers.
    // B layout: lane holds col n = lm, k = lh*8 + j  (j=0..7), per k-step of 16.
    half8v bfrag[2][16];
#pragma unroll
    for (int b = 0; b < 2; ++b) {
        const _Float16* rowp = Z + (size_t)(rbase + b * 32 + lm) * DD + lh * 8;
#pragma unroll
        for (int s = 0; s < 16; ++s)
            bfrag[b][s] = *(const half8v*)(rowp + s * 16);
    }

    float ea0 = 0.f, ea1 = 0.f;
    const int cchunk = ch * CC;
    const bool blockdiag = (ch == (rt >> 1));
    const float KEXP = 2.0f * 1.44269504088896340736f;  // (1/T) * log2(e)

    for (int cs = 0; cs < CSTEPS; ++cs) {
        const int cbase = cchunk + cs * 32;

        __syncthreads();
        // Stage 32 c-rows x 256 k into LDS, XOR-swizzled 16B granules:
        // granule (c, kc) -> lds offset c*256 + (kc ^ (c&7))*8 elems.
#pragma unroll
        for (int it = 0; it < 4; ++it) {
            const int g = tid + it * 256;       // granule id 0..1023
            const int c = g >> 5;
            const int kc = g & 31;
            half8v gv = *(const half8v*)(Z + (size_t)(cbase + c) * DD + kc * 8);
            *(half8v*)(&lds[c * DD + (kc ^ (c & 7)) * 8]) = gv;
        }
        __syncthreads();

        floatx16 c0, c1;
#pragma unroll
        for (int r = 0; r < 16; ++r) { c0[r] = 0.f; c1[r] = 0.f; }

#pragma unroll
        for (int s = 0; s < 16; ++s) {
            // A fragment: lane holds row m = lm, k = lh*8 + j; logical granule 2s+lh.
            const int phys = (2 * s + lh) ^ (lm & 7);
            half8v af = *(const half8v*)(&lds[lm * DD + phys * 8]);
            c0 = __builtin_amdgcn_mfma_f32_32x32x16_f16(af, bfrag[0][s], c0, 0, 0, 0);
            c1 = __builtin_amdgcn_mfma_f32_32x32x16_f16(af, bfrag[1][s], c1, 0, 0, 0);
        }

        // Epilogue: exp2(sim * 2*log2e), mask diagonal, accumulate per-lane.
        const bool m0 = blockdiag && (cbase == rbase);
        const bool m1 = blockdiag && (cbase == rbase + 32);
        if (!(m0 | m1)) {
#pragma unroll
            for (int r = 0; r < 16; ++r) {
                ea0 += __builtin_amdgcn_exp2f(c0[r] * KEXP);
                ea1 += __builtin_amdgcn_exp2f(c1[r] * KEXP);
            }
        } else {
#pragma unroll
            for (int r = 0; r < 16; ++r) {
                const int mrow = (r & 3) + 8 * (r >> 2) + 4 * lh; // MFMA C row index
                float e0 = __builtin_amdgcn_exp2f(c0[r] * KEXP);
                float e1 = __builtin_amdgcn_exp2f(c1[r] * KEXP);
                if (m0 && (mrow == lm)) e0 = 0.f;
                if (m1 && (mrow == lm)) e1 = 0.f;
                ea0 += e0; ea1 += e1;
            }
        }
    }

    // Column (== row, symmetry) totals: combine the two lane-halves.
    ea0 += __shfl_xor(ea0, 32);
    ea1 += __shfl_xor(ea1, 32);
    if (lane < 32) {
        atomicAdd(&rowsum[rbase + lm], ea0);
        atomicAdd(&rowsum[rbase + 32 + lm], ea1);
    }
}

// ---------------- Kernel 3: finalize ----------------------------------------
__global__ __launch_bounds__(256) void nt_finalize(
    const float* __restrict__ rowsum, const float* __restrict__ posPartial,
    float* __restrict__ out)
{
    const int tid = threadIdx.x;
    float acc = 0.f;
#pragma unroll
    for (int it = 0; it < NN / 256; ++it)
        acc += __builtin_amdgcn_logf(rowsum[tid + it * 256]);   // log2
    float pacc = 0.f;
#pragma unroll
    for (int it = 0; it < 4; ++it)
        pacc += posPartial[tid + it * 256];

#pragma unroll
    for (int off = 32; off > 0; off >>= 1) {
        acc  += __shfl_xor(acc,  off);
        pacc += __shfl_xor(pacc, off);
    }
    __shared__ float sa[4], sp[4];
    const int wave = tid >> 6;
    if ((tid & 63) == 0) { sa[wave] = acc; sp[wave] = pacc; }
    __syncthreads();
    if (tid == 0) {
        const float lntot = (sa[0] + sa[1] + sa[2] + sa[3]) * 0.6931471805599453f;
        const float ptot  = sp[0] + sp[1] + sp[2] + sp[3];
        out[0] = (lntot - 4.0f * ptot) * (1.0f / (float)NN);
    }
}

// ---------------- Launch ------------------------------------------------------
extern "C" void kernel_launch(void* const* d_in, const int* in_sizes, int n_in,
                              void* d_out, int out_size, void* d_ws, size_t ws_size,
                              hipStream_t stream) {
    const float* zi = (const float*)d_in[0];
    const float* zj = (const float*)d_in[1];
    float* out = (float*)d_out;

    _Float16* Z = (_Float16*)d_ws;                                  // 4 MB
    float* rowsum = (float*)((char*)d_ws + (size_t)NN * DD * 2);    // 32 KB
    float* posPartial = rowsum + NN;                                // 4 KB

    hipMemsetAsync(rowsum, 0, NN * sizeof(float), stream);
    nt_normalize<<<BB / 4, 256, 0, stream>>>(zi, zj, Z, posPartial);
    nt_simexp<<<NRT * NCH, 256, 0, stream>>>((const _Float16*)Z, rowsum);
    nt_finalize<<<1, 256, 0, stream>>>(rowsum, posPartial, out);
}

// Round 2
// 96.962 us; speedup vs baseline: 1.0319x; 1.0319x over previous
//
#include <hip/hip_runtime.h>
#include <hip/hip_bf16.h>

// NT-Xent (SimCLR) loss, B=4096, D=256, N=8192, T=0.5.
// loss = [ sum_i log(sum_{j!=i} exp(sim_ij * 2)) - 4 * sum_{i<B} pos_i ] / N
// sim symmetric => row sums computed as column sums of MFMA tiles (per-lane).

constexpr int BB = 4096;     // batch
constexpr int NN = 8192;     // 2*batch
constexpr int DD = 256;      // feature dim
constexpr int RT = 256;      // r-rows per block
constexpr int CC = 512;      // c-columns per block chunk
constexpr int NRT = NN / RT; // 32 row tiles
constexpr int NCH = NN / CC; // 16 column chunks
constexpr int CSTEPS = CC / 32;

typedef _Float16 half4v __attribute__((ext_vector_type(4)));
typedef _Float16 half8v __attribute__((ext_vector_type(8)));
typedef float floatx16 __attribute__((ext_vector_type(16)));

// ---------------- Kernel 1: normalize rows -> f16, pos partials, zero rowsum -
__global__ __launch_bounds__(256) void nt_normalize(
    const float* __restrict__ zi, const float* __restrict__ zj,
    _Float16* __restrict__ Z, float* __restrict__ posPartial,
    float* __restrict__ rowsum)
{
    const int lane = threadIdx.x & 63;
    const int wave = threadIdx.x >> 6;
    const int i = blockIdx.x * 4 + wave;   // pair index, < BB

    // Zero rowsum (8192 floats) with the first 32 blocks; simexp runs after
    // this dispatch completes (stream order), so no race.
    if (blockIdx.x < 32) rowsum[blockIdx.x * 256 + threadIdx.x] = 0.f;

    const float4 a = ((const float4*)(zi + (size_t)i * DD))[lane];
    const float4 b = ((const float4*)(zj + (size_t)i * DD))[lane];

    float ssi = a.x*a.x + a.y*a.y + a.z*a.z + a.w*a.w;
    float ssj = b.x*b.x + b.y*b.y + b.z*b.z + b.w*b.w;
    float dd  = a.x*b.x + a.y*b.y + a.z*b.z + a.w*b.w;
#pragma unroll
    for (int off = 32; off > 0; off >>= 1) {
        ssi += __shfl_xor(ssi, off);
        ssj += __shfl_xor(ssj, off);
        dd  += __shfl_xor(dd,  off);
    }
    const float invi = rsqrtf(ssi);
    const float invj = rsqrtf(ssj);

    half4v ha, hb;
    ha.x = (_Float16)(a.x * invi); ha.y = (_Float16)(a.y * invi);
    ha.z = (_Float16)(a.z * invi); ha.w = (_Float16)(a.w * invi);
    hb.x = (_Float16)(b.x * invj); hb.y = (_Float16)(b.y * invj);
    hb.z = (_Float16)(b.z * invj); hb.w = (_Float16)(b.w * invj);

    ((half4v*)(Z + (size_t)i * DD))[lane]        = ha;
    ((half4v*)(Z + (size_t)(BB + i) * DD))[lane] = hb;

    __shared__ float ps[4];
    if (lane == 0) ps[wave] = dd * invi * invj;
    __syncthreads();
    if (threadIdx.x == 0)
        posPartial[blockIdx.x] = ps[0] + ps[1] + ps[2] + ps[3];
}

// ---------------- Kernel 2: fused sim-GEMM + exp + row-sum -------------------
// Grid: NRT * NCH = 512 blocks, 256 threads (4 waves). Each wave owns 64 r-rows
// (2 B-fragment sets of 32 held in registers across whole K=256). c-tiles of 32
// rows staged into LDS (swizzled), register-buffered prefetch of tile cs+1
// overlaps the k-loop of tile cs.
__global__ __launch_bounds__(256, 2) void nt_simexp(
    const _Float16* __restrict__ Z, float* __restrict__ rowsum)
{
    __shared__ _Float16 lds[32 * DD];   // 16 KB, 16B-granule swizzled

    const int bid = blockIdx.x;
    const int rt = bid & (NRT - 1);
    const int ch = bid >> 5;            // NRT == 32
    const int tid = threadIdx.x;
    const int wave = tid >> 6;
    const int lane = tid & 63;
    const int lm = lane & 31;           // MFMA row/col index within 32
    const int lh = lane >> 5;           // half select

    const int rbase = rt * RT + wave * 64;  // this wave's 64 r-rows

    // B fragments for both 32-row sets, all 16 k-steps, held in registers.
    // B layout: lane holds col n = lm, k = lh*8 + j (j=0..7), per k-step of 16.
    half8v bfrag[2][16];
#pragma unroll
    for (int b = 0; b < 2; ++b) {
        const _Float16* rowp = Z + (size_t)(rbase + b * 32 + lm) * DD + lh * 8;
#pragma unroll
        for (int s = 0; s < 16; ++s)
            bfrag[b][s] = *(const half8v*)(rowp + s * 16);
    }

    // Staging granule coords for this thread (4 granules of 16B per tile).
    const int g_c0 = tid >> 5;          // c row for it=0 (c = (tid+256*it)>>5)
    const int g_kc = tid & 31;

    half8v pre[4];
    auto loadTile = [&](int cbase) {
#pragma unroll
        for (int it = 0; it < 4; ++it) {
            const int c = g_c0 + it * 8;
            pre[it] = *(const half8v*)(Z + (size_t)(cbase + c) * DD + g_kc * 8);
        }
    };
    auto storeTile = [&]() {
#pragma unroll
        for (int it = 0; it < 4; ++it) {
            const int c = g_c0 + it * 8;
            *(half8v*)(&lds[c * DD + (g_kc ^ (c & 7)) * 8]) = pre[it];
        }
    };

    float ea0 = 0.f, ea1 = 0.f;
    const int cchunk = ch * CC;
    const bool blockdiag = (ch == (rt >> 1));
    const float KEXP = 2.0f * 1.44269504088896340736f;  // (1/T) * log2(e)

    loadTile(cchunk);
    storeTile();

    for (int cs = 0; cs < CSTEPS; ++cs) {
        const int cbase = cchunk + cs * 32;

        __syncthreads();                      // tile cs visible in LDS
        if (cs + 1 < CSTEPS) loadTile(cchunk + (cs + 1) * 32);  // latency hidden

        floatx16 c0, c1;
#pragma unroll
        for (int r = 0; r < 16; ++r) { c0[r] = 0.f; c1[r] = 0.f; }

#pragma unroll
        for (int s = 0; s < 16; ++s) {
            // A fragment: lane holds row m = lm, k = lh*8 + j; granule 2s+lh.
            const int phys = (2 * s + lh) ^ (lm & 7);
            half8v af = *(const half8v*)(&lds[lm * DD + phys * 8]);
            c0 = __builtin_amdgcn_mfma_f32_32x32x16_f16(af, bfrag[0][s], c0, 0, 0, 0);
            c1 = __builtin_amdgcn_mfma_f32_32x32x16_f16(af, bfrag[1][s], c1, 0, 0, 0);
        }

        // Epilogue: exp2(sim * 2*log2e), mask diagonal, accumulate per-lane.
        const bool m0 = blockdiag && (cbase == rbase);
        const bool m1 = blockdiag && (cbase == rbase + 32);
        if (!(m0 | m1)) {
#pragma unroll
            for (int r = 0; r < 16; ++r) {
                ea0 += __builtin_amdgcn_exp2f(c0[r] * KEXP);
                ea1 += __builtin_amdgcn_exp2f(c1[r] * KEXP);
            }
        } else {
#pragma unroll
            for (int r = 0; r < 16; ++r) {
                const int mrow = (r & 3) + 8 * (r >> 2) + 4 * lh; // MFMA C row
                float e0 = __builtin_amdgcn_exp2f(c0[r] * KEXP);
                float e1 = __builtin_amdgcn_exp2f(c1[r] * KEXP);
                if (m0 && (mrow == lm)) e0 = 0.f;
                if (m1 && (mrow == lm)) e1 = 0.f;
                ea0 += e0; ea1 += e1;
            }
        }

        __syncthreads();                      // all waves done reading tile cs
        if (cs + 1 < CSTEPS) storeTile();     // stage tile cs+1
    }

    // Column (== row, symmetry) totals: combine the two lane-halves.
    ea0 += __shfl_xor(ea0, 32);
    ea1 += __shfl_xor(ea1, 32);
    if (lane < 32) {
        atomicAdd(&rowsum[rbase + lm], ea0);
        atomicAdd(&rowsum[rbase + 32 + lm], ea1);
    }
}

// ---------------- Kernel 3: finalize ----------------------------------------
__global__ __launch_bounds__(256) void nt_finalize(
    const float* __restrict__ rowsum, const float* __restrict__ posPartial,
    float* __restrict__ out)
{
    const int tid = threadIdx.x;
    float acc = 0.f;
#pragma unroll
    for (int it = 0; it < NN / 256; ++it)
        acc += __builtin_amdgcn_logf(rowsum[tid + it * 256]);   // log2
    float pacc = 0.f;
#pragma unroll
    for (int it = 0; it < 4; ++it)
        pacc += posPartial[tid + it * 256];

#pragma unroll
    for (int off = 32; off > 0; off >>= 1) {
        acc  += __shfl_xor(acc,  off);
        pacc += __shfl_xor(pacc, off);
    }
    __shared__ float sa[4], sp[4];
    const int wave = tid >> 6;
    if ((tid & 63) == 0) { sa[wave] = acc; sp[wave] = pacc; }
    __syncthreads();
    if (tid == 0) {
        const float lntot = (sa[0] + sa[1] + sa[2] + sa[3]) * 0.6931471805599453f;
        const float ptot  = sp[0] + sp[1] + sp[2] + sp[3];
        out[0] = (lntot - 4.0f * ptot) * (1.0f / (float)NN);
    }
}

// ---------------- Launch ------------------------------------------------------
extern "C" void kernel_launch(void* const* d_in, const int* in_sizes, int n_in,
                              void* d_out, int out_size, void* d_ws, size_t ws_size,
                              hipStream_t stream) {
    const float* zi = (const float*)d_in[0];
    const float* zj = (const float*)d_in[1];
    float* out = (float*)d_out;

    _Float16* Z = (_Float16*)d_ws;                                  // 4 MB
    float* rowsum = (float*)((char*)d_ws + (size_t)NN * DD * 2);    // 32 KB
    float* posPartial = rowsum + NN;                                // 4 KB

    nt_normalize<<<BB / 4, 256, 0, stream>>>(zi, zj, Z, posPartial, rowsum);
    nt_simexp<<<NRT * NCH, 256, 0, stream>>>((const _Float16*)Z, rowsum);
    nt_finalize<<<1, 256, 0, stream>>>(rowsum, posPartial, out);
}